// Round 19
// baseline (69.099 us; speedup 1.0000x reference)
//
#include <hip/hip_runtime.h>
#include <stdint.h>

// Fused BSQ: recon = sign(x @ Wp + bp) @ Wr + br   (L2-normalize is sign-invariant)
// x: [65536][512] f32, Wp: [512][16], bp: [16], Wr: [16][512], br: [512]
//
// Round-19 = round-18 with TILE 16 -> 8 (occupancy experiment):
//  - Evidence: occupancy pinned at ~36% for both 21KB (r16) and 37KB (r18)
//    LDS -> only ~3 blocks/CU resident vs 4-7 static. Smaller blocks (8192 x
//    8 rows, LDS 18.7KB, 8/CU ceiling) = more independent streams per CU to
//    cover prologue drains + BAR convergence. r12 (32->16) won the same way.
//  - Whole-tile staging: 4 DMAs/wave, no slot reuse, no WAITL. Prologue:
//    ALL weights -> 4 stages -> WAITV(4) (drains weights). Chunks 0..3
//    consume with countdown WAITV(3-c). ONE BAR. Recon rows 0..7: no waits,
//    nt float2 stores (stores never forced to drain).
//  - pk-FMA dot, 2-shuffle cg-reduce, zp[row][d][wave] conflict-free,
//    block-uniform ambiguity mask, rare (~2%) cooperative exact-f64 fixup
//    with matched barriers. Reference signs f64-exact: r1-18 absmax 0.0.

#define ROWS   65536
#define TILE   8
#define BLOCKS (ROWS / TILE)   // 8192
#define TAU    1e-3f

#define BAR()    asm volatile("s_waitcnt lgkmcnt(0)\n\ts_barrier" ::: "memory")
#define WAITV(N) asm volatile("s_waitcnt vmcnt(" #N ")" ::: "memory")
#define CFENCE() asm volatile("" ::: "memory")

typedef const __attribute__((address_space(1))) void* gas1_t;
typedef __attribute__((address_space(3))) void*       las3_t;
typedef float v2f __attribute__((ext_vector_type(2)));

__global__ __launch_bounds__(256, 2)
void bsq_fused(const float* __restrict__ x,
               const float* __restrict__ Wp,
               const float* __restrict__ bp,
               const float* __restrict__ Wr,
               const float* __restrict__ br,
               float* __restrict__ out)
{
    const int tid = threadIdx.x;
    const int w   = tid >> 6;      // wave 0..3: c-quarter
    const int l   = tid & 63;
    const int cg  = l >> 4;        // 0..3
    const int dg  = l & 15;        // 0..15: this lane's d

    __shared__ __align__(16) float  xl[4 * 1024];     // 16 KB: whole 8-row tile
    __shared__ __align__(16) float  zp[TILE][16][4];  // 2 KB: [row][d][wave]
    __shared__ __align__(16) double zb64[4][16];      // fixup exchange

    // ---- ALL weights first: oldest vm ops, drained by the single WAITV(4) ----
    v2f wpA[8], wpB[8];
#pragma unroll
    for (int j = 0; j < 8; ++j) {
        const float* wj = Wp + (w * 128 + j * 16 + cg * 4) * 16 + dg;
        wpA[j] = (v2f){ wj[0],  wj[16] };
        wpB[j] = (v2f){ wj[32], wj[48] };
    }
    const float bpf = bp[dg];
    v2f wrv[16];
    const float2* Wr2 = (const float2*)Wr;
#pragma unroll
    for (int d = 0; d < 16; ++d) {
        const float2 t = Wr2[d * 256 + tid];
        wrv[d] = (v2f){ t.x, t.y };
    }
    const float2 brt = ((const float2*)br)[tid];
    const v2f br2v = (v2f){ brt.x, brt.y };
    CFENCE();

    const int row0 = blockIdx.x * TILE;
    const float* xsrc = x + (size_t)row0 * 512 + (size_t)(l >> 5) * 512
                          + w * 128 + (l & 31) * 4;

    auto stage = [&](int s) {      // rows 2s,2s+1: wave's 1 KB region, 1 DMA
        __builtin_amdgcn_global_load_lds(
            (gas1_t)(xsrc + (size_t)(2 * s) * 512),
            (las3_t)(&xl[s * 1024 + w * 256]), 16, 0, 0);
    };

    auto dot_part = [&](int s, int p, v2f& accA, v2f& accB) {
        const float* bx = &xl[s * 1024 + w * 256 + p * 128 + cg * 4];
        float4 xr[8];
#pragma unroll
        for (int j = 0; j < 8; ++j) xr[j] = *(const float4*)(bx + j * 16);
        accA = (v2f){0.f, 0.f};  accB = (v2f){0.f, 0.f};
#pragma unroll
        for (int j = 0; j < 8; ++j) {
            accA += (v2f){ xr[j].x, xr[j].y } * wpA[j];   // v_pk_fma_f32
            accB += (v2f){ xr[j].z, xr[j].w } * wpB[j];
        }
    };
    auto fin_part = [&](int r, v2f accA, v2f accB) {
        float a = (accA.x + accA.y) + (accB.x + accB.y);
        a += __shfl_xor(a, 16, 64);    // reduce over cg (lane bits 4,5)
        a += __shfl_xor(a, 32, 64);
        if (l < 16) zp[r][l][w] = a;   // 2-way bank alias = free
    };

    // ============ prologue: stage the whole tile, drain weights ============
#pragma unroll
    for (int s = 0; s < 4; ++s) stage(s);
    WAITV(4);   // all weight loads retired; 4 stages outstanding
    CFENCE();

    // ========== Phase A: rows 0..7, countdown waits ==========
    {
        v2f aA0, aB0, aA1, aB1;
        WAITV(3); dot_part(0, 0, aA0, aB0); dot_part(0, 1, aA1, aB1);
        fin_part(0, aA0, aB0); fin_part(1, aA1, aB1);
        WAITV(2); dot_part(1, 0, aA0, aB0); dot_part(1, 1, aA1, aB1);
        fin_part(2, aA0, aB0); fin_part(3, aA1, aB1);
        WAITV(1); dot_part(2, 0, aA0, aB0); dot_part(2, 1, aA1, aB1);
        fin_part(4, aA0, aB0); fin_part(5, aA1, aB1);
        WAITV(0); dot_part(3, 0, aA0, aB0); dot_part(3, 1, aA1, aB1);
        fin_part(6, aA0, aB0); fin_part(7, aA1, aB1);
    }
    BAR();                             // zp visible (lgkm-only)

    // ============ Phase B: recon rows 0..7 (no waits) ============
    uint32_t amb = 0;                  // block-uniform ambiguity mask
    auto recon_row = [&](int r) {
        const float4 q = *(const float4*)&zp[r][dg][0];   // 1 b128, conflict-free
        const float  z = (q.x + q.y) + (q.z + q.w) + bpf;
        if (__ballot(fabsf(z) < TAU)) amb |= (1u << r);
        const int m = (int)(__ballot(z >= 0.0f) & 0xFFFFull);
        v2f o = br2v;
#pragma unroll
        for (int d = 0; d < 16; ++d) {
            const float s = ((m >> d) & 1) ? 1.0f : -1.0f;
            o += (v2f){ s, s } * wrv[d];                  // v_pk_fma_f32
        }
        __builtin_nontemporal_store(
            o, (v2f*)((float2*)out + (size_t)(row0 + r) * 256 + tid));
    };
#pragma unroll 2
    for (int r = 0; r < TILE; ++r) recon_row(r);

    // ===== Fixup: rare exact-f64 redo; uniform loop, matched barriers =====
    const double bpd = (double)bpf;
#pragma unroll 1
    while (amb) {
        const int rr = __ffs(amb) - 1;
        amb &= amb - 1;
        const int row = row0 + rr;

        const float* xp = x + (size_t)row * 512 + w * 128 + cg * 4;
        double ad = 0.0;
#pragma unroll
        for (int j = 0; j < 8; ++j) {
            const float4 xf = *(const float4*)(xp + j * 16);
#pragma unroll
            for (int e = 0; e < 4; ++e) {
                const float wpe = Wp[(w * 128 + j * 16 + cg * 4 + e) * 16 + dg];
                const float xe  = e == 0 ? xf.x : e == 1 ? xf.y
                               : e == 2 ? xf.z : xf.w;
                ad = fma((double)xe, (double)wpe, ad);
            }
        }
        ad += __shfl_xor(ad, 16, 64);
        ad += __shfl_xor(ad, 32, 64);
        if (l < 16) zb64[w][l] = ad;
        BAR();
        const double zd = (zb64[0][dg] + zb64[1][dg])
                        + (zb64[2][dg] + zb64[3][dg]) + bpd;
        const int m = (int)(__ballot(zd >= 0.0) & 0xFFFFull);
        BAR();   // zb64 reads retired before next fixup row's rewrite

        v2f o = br2v;
#pragma unroll
        for (int d = 0; d < 16; ++d) {
            const float s = ((m >> d) & 1) ? 1.0f : -1.0f;
            o += (v2f){ s, s } * wrv[d];
        }
        __builtin_nontemporal_store(
            o, (v2f*)((float2*)out + (size_t)row * 256 + tid));
    }
}

extern "C" void kernel_launch(void* const* d_in, const int* in_sizes, int n_in,
                              void* d_out, int out_size, void* d_ws, size_t ws_size,
                              hipStream_t stream) {
    const float* x  = (const float*)d_in[0];
    const float* Wp = (const float*)d_in[1];
    const float* bp = (const float*)d_in[2];
    const float* Wr = (const float*)d_in[3];
    const float* br = (const float*)d_in[4];
    float* out = (float*)d_out;

    bsq_fused<<<BLOCKS, 256, 0, stream>>>(x, Wp, bp, Wr, br, out);
}

// Round 20
// 59.213 us; speedup vs baseline: 1.1670x; 1.1670x over previous
//
#include <hip/hip_runtime.h>
#include <stdint.h>

// Fused BSQ: recon = sign(x @ Wp + bp) @ Wr + br   (L2-normalize is sign-invariant)
// x: [65536][512] f32, Wp: [512][16], bp: [16], Wr: [16][512], br: [512]
//
// Round-20 = round-18 (best: 61.2us) + two VALU micro-fixes:
//  1) SALU sign-select: mask m is wave-uniform (SGPR). Build the +-1.0f
//     bit-pattern with uniform scalar integer ops (0x3f800000 | sign<<31)
//     so the per-d select runs on the scalar pipe, leaving recon = 16
//     v_pk_fma (one SGPR operand each) instead of 16 cndmask + 16 pk_fma.
//  2) TAU 1e-3 -> 2e-4: f32-dot error here is ~1e-6 (200x margin left);
//     fixup rows drop ~5x (~0.4% of rows).
// Everything else IDENTICAL to r18: whole-tile staging (8 DMAs/wave,
// no slot reuse), weights oldest in vm queue + single WAITV(8) drain,
// countdown WAITV in phase A, counted WAITV(3+k) in the interleaved second
// half, zp[row][d][wave] conflict-free, nt float2 stores, block-uniform
// ambiguity mask, cooperative exact-f64 fixup with matched barriers.
// Reference signs f64-exact: r1-19 absmax 0.0.

#define ROWS   65536
#define TILE   16
#define BLOCKS (ROWS / TILE)   // 4096
#define TAU    2e-4f

#define BAR()    asm volatile("s_waitcnt lgkmcnt(0)\n\ts_barrier" ::: "memory")
#define WAITV(N) asm volatile("s_waitcnt vmcnt(" #N ")" ::: "memory")
#define CFENCE() asm volatile("" ::: "memory")

typedef const __attribute__((address_space(1))) void* gas1_t;
typedef __attribute__((address_space(3))) void*       las3_t;
typedef float v2f __attribute__((ext_vector_type(2)));

__global__ __launch_bounds__(256, 2)
void bsq_fused(const float* __restrict__ x,
               const float* __restrict__ Wp,
               const float* __restrict__ bp,
               const float* __restrict__ Wr,
               const float* __restrict__ br,
               float* __restrict__ out)
{
    const int tid = threadIdx.x;
    const int w   = tid >> 6;      // wave 0..3: c-quarter
    const int l   = tid & 63;
    const int cg  = l >> 4;        // 0..3
    const int dg  = l & 15;        // 0..15: this lane's d

    __shared__ __align__(16) float  xl[8 * 1024];     // 32 KB: whole tile
    __shared__ __align__(16) float  zp[TILE][16][4];  // 4 KB: [row][d][wave]
    __shared__ __align__(16) double zb64[4][16];      // fixup exchange

    // ---- ALL weights first: oldest vm ops, drained by the single WAITV(8) ----
    v2f wpA[8], wpB[8];
#pragma unroll
    for (int j = 0; j < 8; ++j) {
        const float* wj = Wp + (w * 128 + j * 16 + cg * 4) * 16 + dg;
        wpA[j] = (v2f){ wj[0],  wj[16] };
        wpB[j] = (v2f){ wj[32], wj[48] };
    }
    const float bpf = bp[dg];
    v2f wrv[16];
    const float2* Wr2 = (const float2*)Wr;
#pragma unroll
    for (int d = 0; d < 16; ++d) {
        const float2 t = Wr2[d * 256 + tid];
        wrv[d] = (v2f){ t.x, t.y };
    }
    const float2 brt = ((const float2*)br)[tid];
    const v2f br2v = (v2f){ brt.x, brt.y };
    CFENCE();

    const int row0 = blockIdx.x * TILE;
    const float* xsrc = x + (size_t)row0 * 512 + (size_t)(l >> 5) * 512
                          + w * 128 + (l & 31) * 4;

    auto stage = [&](int s) {      // rows 2s,2s+1: wave's 1 KB region, 1 DMA
        __builtin_amdgcn_global_load_lds(
            (gas1_t)(xsrc + (size_t)(2 * s) * 512),
            (las3_t)(&xl[s * 1024 + w * 256]), 16, 0, 0);
    };

    auto dot_part = [&](int s, int p, v2f& accA, v2f& accB) {
        const float* bx = &xl[s * 1024 + w * 256 + p * 128 + cg * 4];
        float4 xr[8];
#pragma unroll
        for (int j = 0; j < 8; ++j) xr[j] = *(const float4*)(bx + j * 16);
        accA = (v2f){0.f, 0.f};  accB = (v2f){0.f, 0.f};
#pragma unroll
        for (int j = 0; j < 8; ++j) {
            accA += (v2f){ xr[j].x, xr[j].y } * wpA[j];   // v_pk_fma_f32
            accB += (v2f){ xr[j].z, xr[j].w } * wpB[j];
        }
    };
    auto fin_part = [&](int r, v2f accA, v2f accB) {
        float a = (accA.x + accA.y) + (accB.x + accB.y);
        a += __shfl_xor(a, 16, 64);    // reduce over cg (lane bits 4,5)
        a += __shfl_xor(a, 32, 64);
        if (l < 16) zp[r][l][w] = a;   // 2-way bank alias = free
    };

    // ============ prologue: stage the WHOLE tile, drain weights ============
#pragma unroll
    for (int s = 0; s < 8; ++s) stage(s);
    WAITV(8);   // all weight loads retired; 8 stages outstanding
    CFENCE();

    // ========== Phase A first half: rows 0..7, countdown waits ==========
    {
        v2f aA0, aB0, aA1, aB1;
        WAITV(7); dot_part(0, 0, aA0, aB0); dot_part(0, 1, aA1, aB1);
        fin_part(0, aA0, aB0); fin_part(1, aA1, aB1);
        WAITV(6); dot_part(1, 0, aA0, aB0); dot_part(1, 1, aA1, aB1);
        fin_part(2, aA0, aB0); fin_part(3, aA1, aB1);
        WAITV(5); dot_part(2, 0, aA0, aB0); dot_part(2, 1, aA1, aB1);
        fin_part(4, aA0, aB0); fin_part(5, aA1, aB1);
        WAITV(4); dot_part(3, 0, aA0, aB0); dot_part(3, 1, aA1, aB1);
        fin_part(6, aA0, aB0); fin_part(7, aA1, aB1);
    }
    BAR();                             // zp rows 0..7 visible (lgkm-only)

    uint32_t amb = 0;                  // block-uniform ambiguity mask
    auto recon_row = [&](int r) {
        const float4 q = *(const float4*)&zp[r][dg][0];   // 1 b128, conflict-free
        const float  z = (q.x + q.y) + (q.z + q.w) + bpf;
        if (__ballot(fabsf(z) < TAU)) amb |= (1u << r);
        const uint32_t m = (uint32_t)(__ballot(z >= 0.0f) & 0xFFFFull);  // SGPR
        v2f o = br2v;
#pragma unroll
        for (int d = 0; d < 16; ++d) {
            // uniform scalar-integer sign select: +1.0f / -1.0f bit pattern
            const uint32_t su = 0x3f800000u | ((~(m >> d) & 1u) << 31);
            const float s = __uint_as_float(su);
            o += (v2f){ s, s } * wrv[d];                  // v_pk_fma (SGPR src)
        }
        __builtin_nontemporal_store(
            o, (v2f*)((float2*)out + (size_t)(row0 + r) * 256 + tid));
    };

    // == Phase A second half (rows 8..15) interleaved with recon rows 0..7 ==
    // Before chunk 4+k: newer-than-stage(4+k) = (3-k) stages + 2k stores
    // -> WAITV(3+k) (stores swap in for stages one-for-one, in-order queue).
    {
        v2f aA0, aB0, aA1, aB1;
        WAITV(3);
        dot_part(4, 0, aA0, aB0); dot_part(4, 1, aA1, aB1);
        fin_part(8, aA0, aB0); fin_part(9, aA1, aB1);
        recon_row(0); recon_row(1);
        WAITV(4);
        dot_part(5, 0, aA0, aB0); dot_part(5, 1, aA1, aB1);
        fin_part(10, aA0, aB0); fin_part(11, aA1, aB1);
        recon_row(2); recon_row(3);
        WAITV(5);
        dot_part(6, 0, aA0, aB0); dot_part(6, 1, aA1, aB1);
        fin_part(12, aA0, aB0); fin_part(13, aA1, aB1);
        recon_row(4); recon_row(5);
        WAITV(6);
        dot_part(7, 0, aA0, aB0); dot_part(7, 1, aA1, aB1);
        fin_part(14, aA0, aB0); fin_part(15, aA1, aB1);
        recon_row(6); recon_row(7);
    }
    BAR();                             // zp rows 8..15 visible

    // ============ Phase B tail: recon rows 8..15 ============
#pragma unroll 2
    for (int r = 8; r < TILE; ++r) recon_row(r);

    // ===== Fixup: rare exact-f64 redo; uniform loop, matched barriers =====
    const double bpd = (double)bpf;
#pragma unroll 1
    while (amb) {
        const int rr = __ffs(amb) - 1;
        amb &= amb - 1;
        const int row = row0 + rr;

        const float* xp = x + (size_t)row * 512 + w * 128 + cg * 4;
        double ad = 0.0;
#pragma unroll
        for (int j = 0; j < 8; ++j) {
            const float4 xf = *(const float4*)(xp + j * 16);
#pragma unroll
            for (int e = 0; e < 4; ++e) {
                const float wpe = Wp[(w * 128 + j * 16 + cg * 4 + e) * 16 + dg];
                const float xe  = e == 0 ? xf.x : e == 1 ? xf.y
                               : e == 2 ? xf.z : xf.w;
                ad = fma((double)xe, (double)wpe, ad);
            }
        }
        ad += __shfl_xor(ad, 16, 64);
        ad += __shfl_xor(ad, 32, 64);
        if (l < 16) zb64[w][l] = ad;
        BAR();
        const double zd = (zb64[0][dg] + zb64[1][dg])
                        + (zb64[2][dg] + zb64[3][dg]) + bpd;
        const uint32_t m = (uint32_t)(__ballot(zd >= 0.0) & 0xFFFFull);
        BAR();   // zb64 reads retired before next fixup row's rewrite

        v2f o = br2v;
#pragma unroll
        for (int d = 0; d < 16; ++d) {
            const uint32_t su = 0x3f800000u | ((~(m >> d) & 1u) << 31);
            const float s = __uint_as_float(su);
            o += (v2f){ s, s } * wrv[d];
        }
        __builtin_nontemporal_store(
            o, (v2f*)((float2*)out + (size_t)row * 256 + tid));
    }
}

extern "C" void kernel_launch(void* const* d_in, const int* in_sizes, int n_in,
                              void* d_out, int out_size, void* d_ws, size_t ws_size,
                              hipStream_t stream) {
    const float* x  = (const float*)d_in[0];
    const float* Wp = (const float*)d_in[1];
    const float* bp = (const float*)d_in[2];
    const float* Wr = (const float*)d_in[3];
    const float* br = (const float*)d_in[4];
    float* out = (float*)d_out;

    bsq_fused<<<BLOCKS, 256, 0, stream>>>(x, Wp, bp, Wr, br, out);
}